// Round 11
// baseline (170982.959 us; speedup 1.0000x reference)
//
#include <hip/hip_runtime.h>
#include <cstddef>

namespace {
constexpr int kH = 16;   // hidden
constexpr int kL = 4;    // layers
constexpr int kF = 256;  // input features
constexpr int kA = 16;   // attention dim
constexpr int kG = 48;   // 3*H gates
}

// Pin a value into a VGPR at this point (opaque to the optimizer).
#define PIN(x) asm volatile("" : "+v"(x))

#if defined(__has_builtin)
#if __has_builtin(__builtin_amdgcn_permlane16_swap) && __has_builtin(__builtin_amdgcn_permlane32_swap)
#define HAVE_PLSWAP 1
#endif
#endif

#ifdef HAVE_PLSWAP
__device__ __forceinline__ float swap_sum32(float x) {
  auto r = __builtin_amdgcn_permlane32_swap(__float_as_uint(x), __float_as_uint(x), false, false);
  return __uint_as_float(r[0]) + __uint_as_float(r[1]);
}
__device__ __forceinline__ float swap_sum16(float x) {
  auto r = __builtin_amdgcn_permlane16_swap(__float_as_uint(x), __float_as_uint(x), false, false);
  return __uint_as_float(r[0]) + __uint_as_float(r[1]);
}
#else
__device__ __forceinline__ float swap_sum32(float x) {
  return x + __shfl(x, (int)(threadIdx.x & 63) ^ 32, 64);
}
__device__ __forceinline__ float swap_sum16(float x) {
  return x + __shfl(x, (int)(threadIdx.x & 63) ^ 16, 64);
}
#endif

// rotate right by J within each 16-lane row (schedulable intrinsic; the
// backend fuses mov_dpp+fmac into v_fmac_f32_dpp and handles hazards).
template <int J>
__device__ __forceinline__ float rotr(float x) {
  return __int_as_float(__builtin_amdgcn_update_dpp(
      0, __float_as_int(x), 0x120 + J, 0xF, 0xF, false));
}
// add value rotated by N within each 16-lane row
template <int CTRL>
__device__ __forceinline__ float ror_add(float x) {
  int r = __builtin_amdgcn_update_dpp(0, __float_as_int(x), CTRL, 0xF, 0xF, false);
  return x + __int_as_float(r);
}
__device__ __forceinline__ float row_sum16(float x) {
  x = ror_add<0x128>(x);  // ror 8
  x = ror_add<0x124>(x);  // ror 4
  x = ror_add<0x122>(x);  // ror 2
  x = ror_add<0x121>(x);  // ror 1
  return x;
}
__device__ __forceinline__ float fast_rcp(float x) { return __builtin_amdgcn_rcpf(x); }
constexpr float kL2E = 1.4426950408889634f;
__device__ __forceinline__ float sigm(float x) {
  return fast_rcp(1.0f + __builtin_amdgcn_exp2f(-kL2E * x));
}
__device__ __forceinline__ float tanh_f(float x) {
  return 1.0f - 2.0f * fast_rcp(1.0f + __builtin_amdgcn_exp2f((2.0f * kL2E) * x));
}

// rotate-dot (R9-verified math, now in schedulable IR): acc = bias +
// sum_j ror(h, j) * w[j], w pre-rotated: w[j][lane a] = W[row(a)][(a-j)&15].
__device__ __forceinline__ float dot16r(const float* w, float h, float bias) {
  float a0 = fmaf(h, w[0], bias);
  float a1 = rotr<1>(h) * w[1];
  float a2 = rotr<2>(h) * w[2];
  float a3 = rotr<3>(h) * w[3];
  a0 = fmaf(rotr<4>(h), w[4], a0);
  a1 = fmaf(rotr<5>(h), w[5], a1);
  a2 = fmaf(rotr<6>(h), w[6], a2);
  a3 = fmaf(rotr<7>(h), w[7], a3);
  a0 = fmaf(rotr<8>(h), w[8], a0);
  a1 = fmaf(rotr<9>(h), w[9], a1);
  a2 = fmaf(rotr<10>(h), w[10], a2);
  a3 = fmaf(rotr<11>(h), w[11], a3);
  a0 = fmaf(rotr<12>(h), w[12], a0);
  a1 = fmaf(rotr<13>(h), w[13], a1);
  a2 = fmaf(rotr<14>(h), w[14], a2);
  a3 = fmaf(rotr<15>(h), w[15], a3);
  return (a0 + a1) + (a2 + a3);
}

// ---------------- Kernel A: gi0T[g][t] = bih0[g] + sum_f batch[t][f]*Wih0[g][f]
__global__ __launch_bounds__(256) void gi0_kernel(
    const float* __restrict__ batch, const float* __restrict__ Wih0,
    const float* __restrict__ bih0, float* __restrict__ gi0T, int T) {
  __shared__ __align__(16) float w[kG * kF];
  __shared__ float bsh[kG];
  for (int i = threadIdx.x; i < kG * kF; i += blockDim.x) w[i] = Wih0[i];
  if (threadIdx.x < kG) bsh[threadIdx.x] = bih0[threadIdx.x];
  __syncthreads();
  int t = blockIdx.x * blockDim.x + threadIdx.x;
  if (t >= T) return;
  float acc[kG];
#pragma unroll
  for (int gg = 0; gg < kG; ++gg) acc[gg] = bsh[gg];
  const float* brow = batch + (size_t)t * kF;
  for (int f = 0; f < kF; f += 4) {
    const float4 b4 = *reinterpret_cast<const float4*>(brow + f);
#pragma unroll
    for (int gg = 0; gg < kG; ++gg) {
      const float4 w4 = *reinterpret_cast<const float4*>(&w[gg * kF + f]);
      acc[gg] = fmaf(b4.x, w4.x, acc[gg]);
      acc[gg] = fmaf(b4.y, w4.y, acc[gg]);
      acc[gg] = fmaf(b4.z, w4.z, acc[gg]);
      acc[gg] = fmaf(b4.w, w4.w, acc[gg]);
    }
  }
#pragma unroll
  for (int gg = 0; gg < kG; ++gg) gi0T[(size_t)gg * T + t] = acc[gg];
}

// ---------------- Kernel B: sequential recurrence (R10 structure, schedulable dots)
__global__ __launch_bounds__(64)
__attribute__((amdgpu_waves_per_eu(1, 1)))
void seq_kernel(
    const float* __restrict__ Whh0, const float* __restrict__ bhh0,
    const float* __restrict__ Wih, const float* __restrict__ Whh,
    const float* __restrict__ bih, const float* __restrict__ bhh,
    const float* __restrict__ aW, const float* __restrict__ ab,
    const float* __restrict__ av, const float* __restrict__ avb,
    const float* __restrict__ gi0T, float* __restrict__ topT, int T) {
  const int lane = threadIdx.x & 63;
  const int grp = lane >> 4;
  const int a = lane & 15;
  const int gr = (grp == 0) ? a : (grp == 2 ? 32 + a : 16 + a);

  // --- per-lane PRE-ROTATED weight rows (R9 layout) ---
  float Wh[kL][kH];
  float Ux[3][kH];
  float aWj[kH];
#pragma unroll
  for (int j = 0; j < kH; ++j) {
    const int idx = (a - j) & 15;
    Wh[0][j] = Whh0[gr * kH + idx];
#pragma unroll
    for (int l = 1; l < kL; ++l) {
      Wh[l][j] = Whh[((l - 1) * kG + gr) * kH + idx];
      Ux[l - 1][j] = Wih[((l - 1) * kG + gr) * kH + idx];
    }
    aWj[j] = aW[(grp * kH + idx) * kA + a];
  }
  float bh[kL], bi[3];
  bh[0] = bhh0[gr];
#pragma unroll
  for (int l = 1; l < kL; ++l) {
    bh[l] = bhh[(l - 1) * kG + gr];
    bi[l - 1] = bih[(l - 1) * kG + gr];
  }
  float abr = ab[grp * kA + a];
  float avr = av[grp * kA + a];
  float avbr = avb[grp];

#pragma unroll
  for (int l = 0; l < kL; ++l) {
#pragma unroll
    for (int k = 0; k < kH; ++k) PIN(Wh[l][k]);
    PIN(bh[l]);
  }
#pragma unroll
  for (int l = 0; l < 3; ++l) {
#pragma unroll
    for (int k = 0; k < kH; ++k) PIN(Ux[l][k]);
    PIN(bi[l]);
  }
#pragma unroll
  for (int k = 0; k < kH; ++k) PIN(aWj[k]);
  PIN(abr); PIN(avr); PIN(avbr);

  float hs = 0.0f;  // packed state: lane 16*l+a holds h[l][a]

  const float* pG = gi0T + (size_t)gr * T;   // per-lane contiguous stream
  float* pT = topT + (size_t)a * T;          // lanes 48..63 store here

  const int NG = T / 4;  // groups of 4 steps
  float4 c4 = *reinterpret_cast<const float4*>(pG + 0);
  float4 n4 = *reinterpret_cast<const float4*>(pG + 4);

#define STEP(gcur, tslot)                                                     \
  {                                                                           \
    float hq[kL];                                                             \
    hq[0] = swap_sum16(swap_sum32(grp == 0 ? hs : 0.0f));                     \
    hq[1] = swap_sum32(swap_sum16(grp == 1 ? hs : 0.0f));                     \
    hq[2] = swap_sum16(swap_sum32(grp == 2 ? hs : 0.0f));                     \
    hq[3] = swap_sum32(swap_sum16(grp == 3 ? hs : 0.0f));                     \
    float xg[kL];                                                             \
    float sc[kL];                                                             \
    _Pragma("unroll")                                                         \
    for (int l = 0; l < kL; ++l) {                                            \
      const float accH = dot16r(Wh[l], hq[l], bh[l]);                         \
      const float accX = (l == 0) ? (gcur)                                    \
                                  : dot16r(Ux[l - 1], xg[l - 1], bi[l - 1]);  \
      const float sg = sigm(accX + accH);                                     \
      const float rv = swap_sum32(grp == 0 ? sg : 0.0f);                      \
      const float zv = swap_sum16(grp == 3 ? sg : 0.0f);                      \
      const float nt = tanh_f(fmaf(rv, accH, accX));                          \
      const float hnew = fmaf(zv, hq[l] - nt, nt);                            \
      xg[l] = swap_sum16(swap_sum32(grp == 2 ? hnew : 0.0f));                 \
      const float d = tanh_f(dot16r(aWj, xg[l], abr));                        \
      sc[l] = row_sum16(d * avr) + avbr;                                      \
    }                                                                         \
    const float s0 = (grp == 0) ? sc[0] : -1e30f;                             \
    const float s1 = (grp <= 1) ? sc[1] : -1e30f;                             \
    const float s2 = (grp <= 2) ? sc[2] : -1e30f;                             \
    const float s3 = sc[3];                                                   \
    const float m = fmaxf(fmaxf(s0, s1), fmaxf(s2, s3));                      \
    const float e0 = __builtin_amdgcn_exp2f((s0 - m) * kL2E);                 \
    const float e1 = __builtin_amdgcn_exp2f((s1 - m) * kL2E);                 \
    const float e2 = __builtin_amdgcn_exp2f((s2 - m) * kL2E);                 \
    const float e3 = __builtin_amdgcn_exp2f((s3 - m) * kL2E);                 \
    const float rden = fast_rcp((e0 + e1) + (e2 + e3));                       \
    float num = e0 * xg[0];                                                   \
    num = fmaf(e1, xg[1], num);                                               \
    num = fmaf(e2, xg[2], num);                                               \
    num = fmaf(e3, xg[3], num);                                               \
    hs = num * rden;                                                          \
    tslot = hs;                                                               \
  }

  for (int g = 0; g < NG; ++g) {
    const int gn = (g + 2 < NG) ? g + 2 : NG - 1;
    const float4 t4 = *reinterpret_cast<const float4*>(pG + (size_t)gn * 4);
    float o0, o1, o2, o3;
    STEP(c4.x, o0)
    STEP(c4.y, o1)
    STEP(c4.z, o2)
    STEP(c4.w, o3)
    if (lane >= 48) {
      *reinterpret_cast<float4*>(pT + (size_t)g * 4) = make_float4(o0, o1, o2, o3);
    }
    c4 = n4;
    n4 = t4;
  }
#undef STEP
}

// ---------------- Kernel C: out[t] = fc2( relu( fc1( topT[:,t] ) ) )
__global__ __launch_bounds__(256) void head_kernel(
    const float* __restrict__ topT, const float* __restrict__ fc1W,
    const float* __restrict__ fc1b, const float* __restrict__ fc2W,
    const float* __restrict__ fc2b, float* __restrict__ out, int T) {
  __shared__ __align__(16) float w1[32 * kH];
  __shared__ float b1[32], w2[32];
  for (int i = threadIdx.x; i < 32 * kH; i += blockDim.x) w1[i] = fc1W[i];
  if (threadIdx.x < 32) {
    b1[threadIdx.x] = fc1b[threadIdx.x];
    w2[threadIdx.x] = fc2W[threadIdx.x];
  }
  __syncthreads();
  int t = blockIdx.x * blockDim.x + threadIdx.x;
  if (t >= T) return;
  float hv[kH];
#pragma unroll
  for (int k = 0; k < kH; ++k) hv[k] = topT[(size_t)k * T + t];
  float o = fc2b[0];
#pragma unroll
  for (int mth = 0; mth < 32; ++mth) {
    float acc = b1[mth];
#pragma unroll
    for (int k = 0; k < kH; ++k) acc = fmaf(hv[k], w1[mth * kH + k], acc);
    acc = fmaxf(acc, 0.0f);
    o = fmaf(acc, w2[mth], o);
  }
  out[t] = o;
}

extern "C" void kernel_launch(void* const* d_in, const int* in_sizes, int n_in,
                              void* d_out, int out_size, void* d_ws, size_t ws_size,
                              hipStream_t stream) {
  const float* batch = (const float*)d_in[0];
  const float* Wih0  = (const float*)d_in[1];
  const float* Whh0  = (const float*)d_in[2];
  const float* bih0  = (const float*)d_in[3];
  const float* bhh0  = (const float*)d_in[4];
  const float* Wih   = (const float*)d_in[5];
  const float* Whh   = (const float*)d_in[6];
  const float* bih   = (const float*)d_in[7];
  const float* bhh   = (const float*)d_in[8];
  const float* aW    = (const float*)d_in[9];
  const float* ab    = (const float*)d_in[10];
  const float* av    = (const float*)d_in[11];
  const float* avb   = (const float*)d_in[12];
  const float* fc1W  = (const float*)d_in[13];
  const float* fc1b  = (const float*)d_in[14];
  const float* fc2W  = (const float*)d_in[15];
  const float* fc2b  = (const float*)d_in[16];
  float* out = (float*)d_out;

  const int T = in_sizes[0] / kF;  // 131072

  // workspace layout: gi0T [48][T] f32 | topT [16][T] f32
  float* gi0T = (float*)d_ws;
  float* topT = gi0T + (size_t)kG * T;

  const int blocks = (T + 255) / 256;
  gi0_kernel<<<blocks, 256, 0, stream>>>(batch, Wih0, bih0, gi0T, T);
  seq_kernel<<<1, 64, 0, stream>>>(Whh0, bhh0, Wih, Whh, bih, bhh,
                                   aW, ab, av, avb, gi0T, topT, T);
  head_kernel<<<blocks, 256, 0, stream>>>(topT, fc1W, fc1b, fc2W, fc2b, out, T);
}

// Round 12
// 125175.879 us; speedup vs baseline: 1.3659x; 1.3659x over previous
//
#include <hip/hip_runtime.h>
#include <cstddef>

namespace {
constexpr int kH = 16;   // hidden
constexpr int kL = 4;    // layers
constexpr int kF = 256;  // input features
constexpr int kA = 16;   // attention dim
constexpr int kG = 48;   // 3*H gates
}

// Pin a value into a VGPR at this point (opaque to the optimizer).
#define PIN(x) asm volatile("" : "+v"(x))

#if defined(__has_builtin)
#if __has_builtin(__builtin_amdgcn_permlane16_swap) && __has_builtin(__builtin_amdgcn_permlane32_swap)
#define HAVE_PLSWAP 1
#endif
#endif

#ifdef HAVE_PLSWAP
__device__ __forceinline__ float swap_sum32(float x) {
  auto r = __builtin_amdgcn_permlane32_swap(__float_as_uint(x), __float_as_uint(x), false, false);
  return __uint_as_float(r[0]) + __uint_as_float(r[1]);
}
__device__ __forceinline__ float swap_sum16(float x) {
  auto r = __builtin_amdgcn_permlane16_swap(__float_as_uint(x), __float_as_uint(x), false, false);
  return __uint_as_float(r[0]) + __uint_as_float(r[1]);
}
#else
__device__ __forceinline__ float swap_sum32(float x) {
  return x + __shfl(x, (int)(threadIdx.x & 63) ^ 32, 64);
}
__device__ __forceinline__ float swap_sum16(float x) {
  return x + __shfl(x, (int)(threadIdx.x & 63) ^ 16, 64);
}
#endif

// add value rotated by N within each 16-lane row (intrinsic — proven in R10)
template <int CTRL>
__device__ __forceinline__ float ror_add(float x) {
  int r = __builtin_amdgcn_update_dpp(0, __float_as_int(x), CTRL, 0xF, 0xF, false);
  return x + __int_as_float(r);
}
__device__ __forceinline__ float row_sum16(float x) {
  x = ror_add<0x128>(x);  // ror 8
  x = ror_add<0x124>(x);  // ror 4
  x = ror_add<0x122>(x);  // ror 2
  x = ror_add<0x121>(x);  // ror 1
  return x;
}
__device__ __forceinline__ float fast_rcp(float x) { return __builtin_amdgcn_rcpf(x); }
constexpr float kL2E = 1.4426950408889634f;
// inputs PRE-SCALED: sigm_pre(x) = 1/(1+2^x)  [x = -log2(e)*pre]
__device__ __forceinline__ float sigm_pre(float x) {
  return fast_rcp(1.0f + __builtin_amdgcn_exp2f(x));
}
// tanh with pre-scaled input: x = 2*log2(e)*arg; tanh = 1 - 2/(2^x+1)
__device__ __forceinline__ float tanh_pre(float x) {
  return 1.0f - 2.0f * fast_rcp(1.0f + __builtin_amdgcn_exp2f(x));
}

// rotate-dot, volatile-asm fused DPP MACs (R10-proven). w pre-rotated:
// w[j][lane a] = W[row(a)][(a-j)&15].
#define FMAC_ROR(acc, h, w, J)                                            \
  asm volatile("v_fmac_f32_dpp %0, %1, %2 row_ror:" #J                    \
               " row_mask:0xf bank_mask:0xf"                              \
               : "+v"(acc) : "v"(h), "v"(w))
#define MUL_ROR(dst, h, w, J)                                             \
  asm volatile("v_mul_f32_dpp %0, %1, %2 row_ror:" #J                     \
               " row_mask:0xf bank_mask:0xf"                              \
               : "=v"(dst) : "v"(h), "v"(w))

// 4-way split (critical-path dots)
__device__ __forceinline__ float dot16r(const float* w, float h, float bias) {
  float a0, a1, a2, a3;
  asm volatile("v_fma_f32 %0, %1, %2, %3" : "=v"(a0) : "v"(h), "v"(w[0]), "v"(bias));
  asm volatile("s_nop 0" ::: );
  MUL_ROR(a1, h, w[1], 1);
  MUL_ROR(a2, h, w[2], 2);
  MUL_ROR(a3, h, w[3], 3);
  FMAC_ROR(a0, h, w[4], 4);
  FMAC_ROR(a1, h, w[5], 5);
  FMAC_ROR(a2, h, w[6], 6);
  FMAC_ROR(a3, h, w[7], 7);
  FMAC_ROR(a0, h, w[8], 8);
  FMAC_ROR(a1, h, w[9], 9);
  FMAC_ROR(a2, h, w[10], 10);
  FMAC_ROR(a3, h, w[11], 11);
  FMAC_ROR(a0, h, w[12], 12);
  FMAC_ROR(a1, h, w[13], 13);
  FMAC_ROR(a2, h, w[14], 14);
  FMAC_ROR(a3, h, w[15], 15);
  return (a0 + a1) + (a2 + a3);
}

// 2-way split (off-critical-path dots: accH, attention) — 2 fewer insts
__device__ __forceinline__ float dot16r2(const float* w, float h, float bias) {
  float a0, a1;
  asm volatile("v_fma_f32 %0, %1, %2, %3" : "=v"(a0) : "v"(h), "v"(w[0]), "v"(bias));
  asm volatile("s_nop 0" ::: );
  MUL_ROR(a1, h, w[1], 1);
  FMAC_ROR(a0, h, w[2], 2);
  FMAC_ROR(a1, h, w[3], 3);
  FMAC_ROR(a0, h, w[4], 4);
  FMAC_ROR(a1, h, w[5], 5);
  FMAC_ROR(a0, h, w[6], 6);
  FMAC_ROR(a1, h, w[7], 7);
  FMAC_ROR(a0, h, w[8], 8);
  FMAC_ROR(a1, h, w[9], 9);
  FMAC_ROR(a0, h, w[10], 10);
  FMAC_ROR(a1, h, w[11], 11);
  FMAC_ROR(a0, h, w[12], 12);
  FMAC_ROR(a1, h, w[13], 13);
  FMAC_ROR(a0, h, w[14], 14);
  FMAC_ROR(a1, h, w[15], 15);
  return a0 + a1;
}

// ---------------- Kernel A: gi0T[g][t] = scale_g * (bih0[g] + batch[t]·Wih0[g])
// r,z rows (g<32) scaled by -log2e; n rows (g>=32) scaled by +2log2e.
__global__ __launch_bounds__(256) void gi0_kernel(
    const float* __restrict__ batch, const float* __restrict__ Wih0,
    const float* __restrict__ bih0, float* __restrict__ gi0T, int T) {
  __shared__ __align__(16) float w[kG * kF];
  __shared__ float bsh[kG];
  for (int i = threadIdx.x; i < kG * kF; i += blockDim.x) w[i] = Wih0[i];
  if (threadIdx.x < kG) bsh[threadIdx.x] = bih0[threadIdx.x];
  __syncthreads();
  int t = blockIdx.x * blockDim.x + threadIdx.x;
  if (t >= T) return;
  float acc[kG];
#pragma unroll
  for (int gg = 0; gg < kG; ++gg) acc[gg] = bsh[gg];
  const float* brow = batch + (size_t)t * kF;
  for (int f = 0; f < kF; f += 4) {
    const float4 b4 = *reinterpret_cast<const float4*>(brow + f);
#pragma unroll
    for (int gg = 0; gg < kG; ++gg) {
      const float4 w4 = *reinterpret_cast<const float4*>(&w[gg * kF + f]);
      acc[gg] = fmaf(b4.x, w4.x, acc[gg]);
      acc[gg] = fmaf(b4.y, w4.y, acc[gg]);
      acc[gg] = fmaf(b4.z, w4.z, acc[gg]);
      acc[gg] = fmaf(b4.w, w4.w, acc[gg]);
    }
  }
#pragma unroll
  for (int gg = 0; gg < kG; ++gg) {
    const float sf = (gg < 32) ? -kL2E : (2.0f * kL2E);
    gi0T[(size_t)gg * T + t] = acc[gg] * sf;
  }
}

// ---------------- Kernel B: sequential recurrence (R10 structure, folded consts)
__global__ __launch_bounds__(64)
__attribute__((amdgpu_waves_per_eu(1, 1)))
void seq_kernel(
    const float* __restrict__ Whh0, const float* __restrict__ bhh0,
    const float* __restrict__ Wih, const float* __restrict__ Whh,
    const float* __restrict__ bih, const float* __restrict__ bhh,
    const float* __restrict__ aW, const float* __restrict__ ab,
    const float* __restrict__ av, const float* __restrict__ avb,
    const float* __restrict__ gi0T, float* __restrict__ topT, int T) {
  const int lane = threadIdx.x & 63;
  const int grp = lane >> 4;
  const int a = lane & 15;
  const int gr = (grp == 0) ? a : (grp == 2 ? 32 + a : 16 + a);
  // per-lane weight scale: n-row lanes (grp==2) use +2k, gate rows use -k
  const float sf = (grp == 2) ? (2.0f * kL2E) : -kL2E;

  // --- per-lane PRE-ROTATED, PRE-SCALED weight rows ---
  float Wh[kL][kH];
  float Ux[3][kH];
  float aWj[kH];
#pragma unroll
  for (int j = 0; j < kH; ++j) {
    const int idx = (a - j) & 15;
    Wh[0][j] = Whh0[gr * kH + idx] * sf;
#pragma unroll
    for (int l = 1; l < kL; ++l) {
      Wh[l][j] = Whh[((l - 1) * kG + gr) * kH + idx] * sf;
      Ux[l - 1][j] = Wih[((l - 1) * kG + gr) * kH + idx] * sf;
    }
    aWj[j] = aW[(grp * kH + idx) * kA + a] * (2.0f * kL2E);
  }
  float bh[kL], bi[3];
  bh[0] = bhh0[gr] * sf;
#pragma unroll
  for (int l = 1; l < kL; ++l) {
    bh[l] = bhh[(l - 1) * kG + gr] * sf;
    bi[l - 1] = bih[(l - 1) * kG + gr] * sf;
  }
  float abr = ab[grp * kA + a] * (2.0f * kL2E);
  // attention value weights folded with softmax log2e; avb cancels in softmax
  float avrA = av[grp * kA + a] * kL2E;
  float avrB = -2.0f * avrA;
  // softmax validity masks (uniform per row)
  float msk0 = (grp == 0) ? 1.0f : 0.0f;
  float msk1 = (grp <= 1) ? 1.0f : 0.0f;
  float msk2 = (grp <= 2) ? 1.0f : 0.0f;

#pragma unroll
  for (int l = 0; l < kL; ++l) {
#pragma unroll
    for (int k = 0; k < kH; ++k) PIN(Wh[l][k]);
    PIN(bh[l]);
  }
#pragma unroll
  for (int l = 0; l < 3; ++l) {
#pragma unroll
    for (int k = 0; k < kH; ++k) PIN(Ux[l][k]);
    PIN(bi[l]);
  }
#pragma unroll
  for (int k = 0; k < kH; ++k) PIN(aWj[k]);
  PIN(abr); PIN(avrA); PIN(avrB);
  PIN(msk0); PIN(msk1); PIN(msk2);

  float hs = 0.0f;  // packed state: lane 16*l+a holds h[l][a]

  const float* pG = gi0T + (size_t)gr * T;   // per-lane contiguous stream
  float* pT = topT + (size_t)a * T;          // lanes 48..63 store here

  const int NG = T / 4;  // groups of 4 steps
  float4 c4 = *reinterpret_cast<const float4*>(pG + 0);
  float4 n4 = *reinterpret_cast<const float4*>(pG + 4);

#define STEP(gcur, tslot)                                                     \
  {                                                                           \
    float hq[kL];                                                             \
    hq[0] = swap_sum16(swap_sum32(grp == 0 ? hs : 0.0f));                     \
    hq[1] = swap_sum32(swap_sum16(grp == 1 ? hs : 0.0f));                     \
    hq[2] = swap_sum16(swap_sum32(grp == 2 ? hs : 0.0f));                     \
    hq[3] = swap_sum32(swap_sum16(grp == 3 ? hs : 0.0f));                     \
    float xg[kL];                                                             \
    float sc[kL];                                                             \
    _Pragma("unroll")                                                         \
    for (int l = 0; l < kL; ++l) {                                            \
      const float accH = dot16r2(Wh[l], hq[l], bh[l]);                        \
      const float accX = (l == 0) ? (gcur)                                    \
                                  : dot16r(Ux[l - 1], xg[l - 1], bi[l - 1]);  \
      const float sg = sigm_pre(accX + accH);          /* r row0, z rows1,3 */\
      const float rv = swap_sum32(grp == 0 ? sg : 0.0f);                      \
      const float zv = swap_sum16(grp == 3 ? sg : 0.0f);                      \
      const float nt = tanh_pre(fmaf(rv, accH, accX)); /* n in row2 */        \
      const float hnew = fmaf(zv, hq[l] - nt, nt);     /* valid row2 */       \
      xg[l] = swap_sum16(swap_sum32(grp == 2 ? hnew : 0.0f));                 \
      /* attention: u = 1/(1+2^dot); d*k*av = fma(u, avrB, avrA) */           \
      const float dv = dot16r2(aWj, xg[l], abr);                              \
      const float u = fast_rcp(1.0f + __builtin_amdgcn_exp2f(dv));            \
      sc[l] = row_sum16(fmaf(u, avrB, avrA));                                 \
    }                                                                         \
    /* softmax (bounded scores: no max-sub; avb cancels) */                   \
    const float e0 = __builtin_amdgcn_exp2f(sc[0]) * msk0;                    \
    const float e1 = __builtin_amdgcn_exp2f(sc[1]) * msk1;                    \
    const float e2 = __builtin_amdgcn_exp2f(sc[2]) * msk2;                    \
    const float e3 = __builtin_amdgcn_exp2f(sc[3]);                           \
    const float rden = fast_rcp((e0 + e1) + (e2 + e3));                       \
    float num = e0 * xg[0];                                                   \
    num = fmaf(e1, xg[1], num);                                               \
    num = fmaf(e2, xg[2], num);                                               \
    num = fmaf(e3, xg[3], num);                                               \
    hs = num * rden;                                                          \
    tslot = hs;                                                               \
  }

  for (int g = 0; g < NG; ++g) {
    const int gn = (g + 2 < NG) ? g + 2 : NG - 1;
    const float4 t4 = *reinterpret_cast<const float4*>(pG + (size_t)gn * 4);
    float o0, o1, o2, o3;
    STEP(c4.x, o0)
    STEP(c4.y, o1)
    STEP(c4.z, o2)
    STEP(c4.w, o3)
    if (lane >= 48) {
      *reinterpret_cast<float4*>(pT + (size_t)g * 4) = make_float4(o0, o1, o2, o3);
    }
    c4 = n4;
    n4 = t4;
  }
#undef STEP
}

// ---------------- Kernel C: out[t] = fc2( relu( fc1( topT[:,t] ) ) )
__global__ __launch_bounds__(256) void head_kernel(
    const float* __restrict__ topT, const float* __restrict__ fc1W,
    const float* __restrict__ fc1b, const float* __restrict__ fc2W,
    const float* __restrict__ fc2b, float* __restrict__ out, int T) {
  __shared__ __align__(16) float w1[32 * kH];
  __shared__ float b1[32], w2[32];
  for (int i = threadIdx.x; i < 32 * kH; i += blockDim.x) w1[i] = fc1W[i];
  if (threadIdx.x < 32) {
    b1[threadIdx.x] = fc1b[threadIdx.x];
    w2[threadIdx.x] = fc2W[threadIdx.x];
  }
  __syncthreads();
  int t = blockIdx.x * blockDim.x + threadIdx.x;
  if (t >= T) return;
  float hv[kH];
#pragma unroll
  for (int k = 0; k < kH; ++k) hv[k] = topT[(size_t)k * T + t];
  float o = fc2b[0];
#pragma unroll
  for (int mth = 0; mth < 32; ++mth) {
    float acc = b1[mth];
#pragma unroll
    for (int k = 0; k < kH; ++k) acc = fmaf(hv[k], w1[mth * kH + k], acc);
    acc = fmaxf(acc, 0.0f);
    o = fmaf(acc, w2[mth], o);
  }
  out[t] = o;
}

extern "C" void kernel_launch(void* const* d_in, const int* in_sizes, int n_in,
                              void* d_out, int out_size, void* d_ws, size_t ws_size,
                              hipStream_t stream) {
  const float* batch = (const float*)d_in[0];
  const float* Wih0  = (const float*)d_in[1];
  const float* Whh0  = (const float*)d_in[2];
  const float* bih0  = (const float*)d_in[3];
  const float* bhh0  = (const float*)d_in[4];
  const float* Wih   = (const float*)d_in[5];
  const float* Whh   = (const float*)d_in[6];
  const float* bih   = (const float*)d_in[7];
  const float* bhh   = (const float*)d_in[8];
  const float* aW    = (const float*)d_in[9];
  const float* ab    = (const float*)d_in[10];
  const float* av    = (const float*)d_in[11];
  const float* avb   = (const float*)d_in[12];
  const float* fc1W  = (const float*)d_in[13];
  const float* fc1b  = (const float*)d_in[14];
  const float* fc2W  = (const float*)d_in[15];
  const float* fc2b  = (const float*)d_in[16];
  float* out = (float*)d_out;

  const int T = in_sizes[0] / kF;  // 131072

  // workspace layout: gi0T [48][T] f32 | topT [16][T] f32
  float* gi0T = (float*)d_ws;
  float* topT = gi0T + (size_t)kG * T;

  const int blocks = (T + 255) / 256;
  gi0_kernel<<<blocks, 256, 0, stream>>>(batch, Wih0, bih0, gi0T, T);
  seq_kernel<<<1, 64, 0, stream>>>(Whh0, bhh0, Wih, Whh, bih, bhh,
                                   aW, ab, av, avb, gi0T, topT, T);
  head_kernel<<<blocks, 256, 0, stream>>>(topT, fc1W, fc1b, fc2W, fc2b, out, T);
}

// Round 13
// 120000.500 us; speedup vs baseline: 1.4249x; 1.0431x over previous
//
#include <hip/hip_runtime.h>
#include <cstddef>

namespace {
constexpr int kH = 16;   // hidden
constexpr int kL = 4;    // layers
constexpr int kF = 256;  // input features
constexpr int kA = 16;   // attention dim
constexpr int kG = 48;   // 3*H gates
}

// Pin a value into a VGPR at this point (opaque to the optimizer).
#define PIN(x) asm volatile("" : "+v"(x))

#if defined(__has_builtin)
#if __has_builtin(__builtin_amdgcn_permlane16_swap) && __has_builtin(__builtin_amdgcn_permlane32_swap)
#define HAVE_PLSWAP 1
#endif
#endif

#ifdef HAVE_PLSWAP
__device__ __forceinline__ float swap_sum32(float x) {
  auto r = __builtin_amdgcn_permlane32_swap(__float_as_uint(x), __float_as_uint(x), false, false);
  return __uint_as_float(r[0]) + __uint_as_float(r[1]);
}
__device__ __forceinline__ float swap_sum16(float x) {
  auto r = __builtin_amdgcn_permlane16_swap(__float_as_uint(x), __float_as_uint(x), false, false);
  return __uint_as_float(r[0]) + __uint_as_float(r[1]);
}
#else
__device__ __forceinline__ float swap_sum32(float x) {
  return x + __shfl(x, (int)(threadIdx.x & 63) ^ 32, 64);
}
__device__ __forceinline__ float swap_sum16(float x) {
  return x + __shfl(x, (int)(threadIdx.x & 63) ^ 16, 64);
}
#endif

// add value rotated by N within each 16-lane row
template <int CTRL>
__device__ __forceinline__ float ror_add(float x) {
  int r = __builtin_amdgcn_update_dpp(0, __float_as_int(x), CTRL, 0xF, 0xF, false);
  return x + __int_as_float(r);
}
__device__ __forceinline__ float row_sum16(float x) {
  x = ror_add<0x128>(x);  // ror 8
  x = ror_add<0x124>(x);  // ror 4
  x = ror_add<0x122>(x);  // ror 2
  x = ror_add<0x121>(x);  // ror 1
  return x;
}
__device__ __forceinline__ float fast_rcp(float x) { return __builtin_amdgcn_rcpf(x); }
constexpr float kL2E = 1.4426950408889634f;
// inputs PRE-SCALED: sigm_pre(x) = 1/(1+2^x)  [x = -log2(e)*pre]
__device__ __forceinline__ float sigm_pre(float x) {
  return fast_rcp(1.0f + __builtin_amdgcn_exp2f(x));
}
// tanh with pre-scaled input: x = 2*log2(e)*arg; tanh = 1 - 2/(2^x+1)
__device__ __forceinline__ float tanh_pre(float x) {
  return 1.0f - 2.0f * fast_rcp(1.0f + __builtin_amdgcn_exp2f(x));
}

// fused DPP MAC (R10-proven). w pre-rotated: w[j][lane a] = W[row(a)][(a-j)&15].
#define FMAC_ROR(acc, h, w, J)                                            \
  asm volatile("v_fmac_f32_dpp %0, %1, %2 row_ror:" #J                    \
               " row_mask:0xf bank_mask:0xf"                              \
               : "+v"(acc) : "v"(h), "v"(w))
#define MUL_ROR(dst, h, w, J)                                             \
  asm volatile("v_mul_f32_dpp %0, %1, %2 row_ror:" #J                     \
               " row_mask:0xf bank_mask:0xf"                              \
               : "=v"(dst) : "v"(h), "v"(w))

// 4 interleaved independent 16-dots (1 acc each, dep distance 4 -> no stalls)
__device__ __forceinline__ void dot16r_x4(
    const float* wA, const float* wB, const float* wC, const float* wD,
    float hA, float hB, float hC, float hD,
    float bA, float bB, float bC, float bD,
    float& oA, float& oB, float& oC, float& oD) {
  float a = fmaf(hA, wA[0], bA);
  float b = fmaf(hB, wB[0], bB);
  float c = fmaf(hC, wC[0], bC);
  float d = fmaf(hD, wD[0], bD);
#define R4(J)                                                             \
  FMAC_ROR(a, hA, wA[J], J); FMAC_ROR(b, hB, wB[J], J);                   \
  FMAC_ROR(c, hC, wC[J], J); FMAC_ROR(d, hD, wD[J], J)
  R4(1); R4(2); R4(3); R4(4); R4(5); R4(6); R4(7);
  R4(8); R4(9); R4(10); R4(11); R4(12); R4(13); R4(14); R4(15);
#undef R4
  oA = a; oB = b; oC = c; oD = d;
}

// 2 interleaved independent 16-dots (2 accs each, dep distance 4)
__device__ __forceinline__ void dot16r_x2(
    const float* wA, float hA, float bA,
    const float* wB, float hB, float bB,
    float& oA, float& oB) {
  float a0 = fmaf(hA, wA[0], bA);
  float b0 = fmaf(hB, wB[0], bB);
  float a1, b1;
  asm volatile("s_nop 0" ::: );
  MUL_ROR(a1, hA, wA[1], 1); MUL_ROR(b1, hB, wB[1], 1);
#define R2(J0, J1)                                                        \
  FMAC_ROR(a0, hA, wA[J0], J0); FMAC_ROR(b0, hB, wB[J0], J0);             \
  FMAC_ROR(a1, hA, wA[J1], J1); FMAC_ROR(b1, hB, wB[J1], J1)
  R2(2, 3); R2(4, 5); R2(6, 7); R2(8, 9); R2(10, 11); R2(12, 13); R2(14, 15);
#undef R2
  oA = a0 + a1;
  oB = b0 + b1;
}

// solo dot (tail attention), 2-acc
__device__ __forceinline__ float dot16r2(const float* w, float h, float bias) {
  float a0, a1;
  asm volatile("v_fma_f32 %0, %1, %2, %3" : "=v"(a0) : "v"(h), "v"(w[0]), "v"(bias));
  asm volatile("s_nop 0" ::: );
  MUL_ROR(a1, h, w[1], 1);
  FMAC_ROR(a0, h, w[2], 2);
  FMAC_ROR(a1, h, w[3], 3);
  FMAC_ROR(a0, h, w[4], 4);
  FMAC_ROR(a1, h, w[5], 5);
  FMAC_ROR(a0, h, w[6], 6);
  FMAC_ROR(a1, h, w[7], 7);
  FMAC_ROR(a0, h, w[8], 8);
  FMAC_ROR(a1, h, w[9], 9);
  FMAC_ROR(a0, h, w[10], 10);
  FMAC_ROR(a1, h, w[11], 11);
  FMAC_ROR(a0, h, w[12], 12);
  FMAC_ROR(a1, h, w[13], 13);
  FMAC_ROR(a0, h, w[14], 14);
  FMAC_ROR(a1, h, w[15], 15);
  return a0 + a1;
}

// ---------------- Kernel A: gi0T[g][t] = scale_g * (bih0[g] + batch[t]·Wih0[g])
__global__ __launch_bounds__(256) void gi0_kernel(
    const float* __restrict__ batch, const float* __restrict__ Wih0,
    const float* __restrict__ bih0, float* __restrict__ gi0T, int T) {
  __shared__ __align__(16) float w[kG * kF];
  __shared__ float bsh[kG];
  for (int i = threadIdx.x; i < kG * kF; i += blockDim.x) w[i] = Wih0[i];
  if (threadIdx.x < kG) bsh[threadIdx.x] = bih0[threadIdx.x];
  __syncthreads();
  int t = blockIdx.x * blockDim.x + threadIdx.x;
  if (t >= T) return;
  float acc[kG];
#pragma unroll
  for (int gg = 0; gg < kG; ++gg) acc[gg] = bsh[gg];
  const float* brow = batch + (size_t)t * kF;
  for (int f = 0; f < kF; f += 4) {
    const float4 b4 = *reinterpret_cast<const float4*>(brow + f);
#pragma unroll
    for (int gg = 0; gg < kG; ++gg) {
      const float4 w4 = *reinterpret_cast<const float4*>(&w[gg * kF + f]);
      acc[gg] = fmaf(b4.x, w4.x, acc[gg]);
      acc[gg] = fmaf(b4.y, w4.y, acc[gg]);
      acc[gg] = fmaf(b4.z, w4.z, acc[gg]);
      acc[gg] = fmaf(b4.w, w4.w, acc[gg]);
    }
  }
#pragma unroll
  for (int gg = 0; gg < kG; ++gg) {
    const float sf = (gg < 32) ? -kL2E : (2.0f * kL2E);
    gi0T[(size_t)gg * T + t] = acc[gg] * sf;
  }
}

// ---------------- Kernel B: sequential recurrence (R12 math, ILP-scheduled)
__global__ __launch_bounds__(64)
__attribute__((amdgpu_waves_per_eu(1, 1)))
__attribute__((amdgpu_flat_work_group_size(64, 64)))
void seq_kernel(
    const float* __restrict__ Whh0, const float* __restrict__ bhh0,
    const float* __restrict__ Wih, const float* __restrict__ Whh,
    const float* __restrict__ bih, const float* __restrict__ bhh,
    const float* __restrict__ aW, const float* __restrict__ ab,
    const float* __restrict__ av, const float* __restrict__ avb,
    const float* __restrict__ gi0T, float* __restrict__ topT, int T) {
  const int lane = threadIdx.x & 63;
  const int grp = lane >> 4;
  const int a = lane & 15;
  const int gr = (grp == 0) ? a : (grp == 2 ? 32 + a : 16 + a);
  const float sf = (grp == 2) ? (2.0f * kL2E) : -kL2E;

  // --- per-lane PRE-ROTATED, PRE-SCALED weight rows ---
  float Wh[kL][kH];
  float Ux[3][kH];
  float aWj[kH];
#pragma unroll
  for (int j = 0; j < kH; ++j) {
    const int idx = (a - j) & 15;
    Wh[0][j] = Whh0[gr * kH + idx] * sf;
#pragma unroll
    for (int l = 1; l < kL; ++l) {
      Wh[l][j] = Whh[((l - 1) * kG + gr) * kH + idx] * sf;
      Ux[l - 1][j] = Wih[((l - 1) * kG + gr) * kH + idx] * sf;
    }
    aWj[j] = aW[(grp * kH + idx) * kA + a] * (2.0f * kL2E);
  }
  float bh[kL], bi[3];
  bh[0] = bhh0[gr] * sf;
#pragma unroll
  for (int l = 1; l < kL; ++l) {
    bh[l] = bhh[(l - 1) * kG + gr] * sf;
    bi[l - 1] = bih[(l - 1) * kG + gr] * sf;
  }
  float abr = ab[grp * kA + a] * (2.0f * kL2E);
  float avrA = av[grp * kA + a] * kL2E;
  float avrB = -2.0f * avrA;
  float msk0 = (grp == 0) ? 1.0f : 0.0f;
  float msk1 = (grp <= 1) ? 1.0f : 0.0f;
  float msk2 = (grp <= 2) ? 1.0f : 0.0f;

#pragma unroll
  for (int l = 0; l < kL; ++l) {
#pragma unroll
    for (int k = 0; k < kH; ++k) PIN(Wh[l][k]);
    PIN(bh[l]);
  }
#pragma unroll
  for (int l = 0; l < 3; ++l) {
#pragma unroll
    for (int k = 0; k < kH; ++k) PIN(Ux[l][k]);
    PIN(bi[l]);
  }
#pragma unroll
  for (int k = 0; k < kH; ++k) PIN(aWj[k]);
  PIN(abr); PIN(avrA); PIN(avrB);
  PIN(msk0); PIN(msk1); PIN(msk2);

  float hs = 0.0f;  // packed state: lane 16*l+a holds h[l][a]

  const float* pG = gi0T + (size_t)gr * T;   // per-lane contiguous stream
  float* pT = topT + (size_t)a * T;          // lanes 48..63 store here

  const int NG = T / 4;  // groups of 4 steps
  float4 c4 = *reinterpret_cast<const float4*>(pG + 0);
  float4 n4 = *reinterpret_cast<const float4*>(pG + 4);

#define STEP(gcur, tslot)                                                     \
  {                                                                           \
    const float hq0 = swap_sum16(swap_sum32(grp == 0 ? hs : 0.0f));           \
    const float hq1 = swap_sum32(swap_sum16(grp == 1 ? hs : 0.0f));           \
    const float hq2 = swap_sum16(swap_sum32(grp == 2 ? hs : 0.0f));           \
    const float hq3 = swap_sum32(swap_sum16(grp == 3 ? hs : 0.0f));           \
    float accH0, accH1, accH2, accH3;                                         \
    dot16r_x4(Wh[0], Wh[1], Wh[2], Wh[3], hq0, hq1, hq2, hq3,                 \
              bh[0], bh[1], bh[2], bh[3], accH0, accH1, accH2, accH3);        \
    /* layer 0 */                                                             \
    float sg = sigm_pre((gcur) + accH0);                                      \
    float rv = swap_sum32(grp == 0 ? sg : 0.0f);                              \
    float zv = swap_sum16(grp == 3 ? sg : 0.0f);                              \
    float nt = tanh_pre(fmaf(rv, accH0, (gcur)));                             \
    float hnew = fmaf(zv, hq0 - nt, nt);                                      \
    const float xg0 = swap_sum16(swap_sum32(grp == 2 ? hnew : 0.0f));         \
    /* layer 1 dot || attn0 dot (both depend only on xg0) */                  \
    float accX1, dv0;                                                         \
    dot16r_x2(Ux[0], xg0, bi[0], aWj, xg0, abr, accX1, dv0);                  \
    const float u0 = fast_rcp(1.0f + __builtin_amdgcn_exp2f(dv0));            \
    sg = sigm_pre(accX1 + accH1);                                             \
    const float sc0 = row_sum16(fmaf(u0, avrB, avrA));                        \
    rv = swap_sum32(grp == 0 ? sg : 0.0f);                                    \
    zv = swap_sum16(grp == 3 ? sg : 0.0f);                                    \
    nt = tanh_pre(fmaf(rv, accH1, accX1));                                    \
    hnew = fmaf(zv, hq1 - nt, nt);                                            \
    const float xg1 = swap_sum16(swap_sum32(grp == 2 ? hnew : 0.0f));         \
    /* layer 2 dot || attn1 dot */                                            \
    float accX2, dv1;                                                         \
    dot16r_x2(Ux[1], xg1, bi[1], aWj, xg1, abr, accX2, dv1);                  \
    const float u1 = fast_rcp(1.0f + __builtin_amdgcn_exp2f(dv1));            \
    sg = sigm_pre(accX2 + accH2);                                             \
    const float sc1 = row_sum16(fmaf(u1, avrB, avrA));                        \
    rv = swap_sum32(grp == 0 ? sg : 0.0f);                                    \
    zv = swap_sum16(grp == 3 ? sg : 0.0f);                                    \
    nt = tanh_pre(fmaf(rv, accH2, accX2));                                    \
    hnew = fmaf(zv, hq2 - nt, nt);                                            \
    const float xg2 = swap_sum16(swap_sum32(grp == 2 ? hnew : 0.0f));         \
    /* layer 3 dot || attn2 dot */                                            \
    float accX3, dv2;                                                         \
    dot16r_x2(Ux[2], xg2, bi[2], aWj, xg2, abr, accX3, dv2);                  \
    const float u2 = fast_rcp(1.0f + __builtin_amdgcn_exp2f(dv2));            \
    sg = sigm_pre(accX3 + accH3);                                             \
    const float sc2 = row_sum16(fmaf(u2, avrB, avrA));                        \
    rv = swap_sum32(grp == 0 ? sg : 0.0f);                                    \
    zv = swap_sum16(grp == 3 ? sg : 0.0f);                                    \
    nt = tanh_pre(fmaf(rv, accH3, accX3));                                    \
    hnew = fmaf(zv, hq3 - nt, nt);                                            \
    const float xg3 = swap_sum16(swap_sum32(grp == 2 ? hnew : 0.0f));         \
    /* attn3 (tail) */                                                        \
    const float dv3 = dot16r2(aWj, xg3, abr);                                 \
    const float u3 = fast_rcp(1.0f + __builtin_amdgcn_exp2f(dv3));            \
    const float sc3 = row_sum16(fmaf(u3, avrB, avrA));                        \
    /* softmax (bounded scores; avb cancels) & mix */                         \
    const float e0 = __builtin_amdgcn_exp2f(sc0) * msk0;                      \
    const float e1 = __builtin_amdgcn_exp2f(sc1) * msk1;                      \
    const float e2 = __builtin_amdgcn_exp2f(sc2) * msk2;                      \
    const float e3 = __builtin_amdgcn_exp2f(sc3);                             \
    const float rden = fast_rcp((e0 + e1) + (e2 + e3));                       \
    float num = e0 * xg0;                                                     \
    num = fmaf(e1, xg1, num);                                                 \
    num = fmaf(e2, xg2, num);                                                 \
    num = fmaf(e3, xg3, num);                                                 \
    hs = num * rden;                                                          \
    tslot = hs;                                                               \
  }

  for (int g = 0; g < NG; ++g) {
    const int gn = (g + 2 < NG) ? g + 2 : NG - 1;
    const float4 t4 = *reinterpret_cast<const float4*>(pG + (size_t)gn * 4);
    float o0, o1, o2, o3;
    STEP(c4.x, o0)
    STEP(c4.y, o1)
    STEP(c4.z, o2)
    STEP(c4.w, o3)
    if (lane >= 48) {
      *reinterpret_cast<float4*>(pT + (size_t)g * 4) = make_float4(o0, o1, o2, o3);
    }
    c4 = n4;
    n4 = t4;
  }
#undef STEP
}

// ---------------- Kernel C: out[t] = fc2( relu( fc1( topT[:,t] ) ) )
__global__ __launch_bounds__(256) void head_kernel(
    const float* __restrict__ topT, const float* __restrict__ fc1W,
    const float* __restrict__ fc1b, const float* __restrict__ fc2W,
    const float* __restrict__ fc2b, float* __restrict__ out, int T) {
  __shared__ __align__(16) float w1[32 * kH];
  __shared__ float b1[32], w2[32];
  for (int i = threadIdx.x; i < 32 * kH; i += blockDim.x) w1[i] = fc1W[i];
  if (threadIdx.x < 32) {
    b1[threadIdx.x] = fc1b[threadIdx.x];
    w2[threadIdx.x] = fc2W[threadIdx.x];
  }
  __syncthreads();
  int t = blockIdx.x * blockDim.x + threadIdx.x;
  if (t >= T) return;
  float hv[kH];
#pragma unroll
  for (int k = 0; k < kH; ++k) hv[k] = topT[(size_t)k * T + t];
  float o = fc2b[0];
#pragma unroll
  for (int mth = 0; mth < 32; ++mth) {
    float acc = b1[mth];
#pragma unroll
    for (int k = 0; k < kH; ++k) acc = fmaf(hv[k], w1[mth * kH + k], acc);
    acc = fmaxf(acc, 0.0f);
    o = fmaf(acc, w2[mth], o);
  }
  out[t] = o;
}

extern "C" void kernel_launch(void* const* d_in, const int* in_sizes, int n_in,
                              void* d_out, int out_size, void* d_ws, size_t ws_size,
                              hipStream_t stream) {
  const float* batch = (const float*)d_in[0];
  const float* Wih0  = (const float*)d_in[1];
  const float* Whh0  = (const float*)d_in[2];
  const float* bih0  = (const float*)d_in[3];
  const float* bhh0  = (const float*)d_in[4];
  const float* Wih   = (const float*)d_in[5];
  const float* Whh   = (const float*)d_in[6];
  const float* bih   = (const float*)d_in[7];
  const float* bhh   = (const float*)d_in[8];
  const float* aW    = (const float*)d_in[9];
  const float* ab    = (const float*)d_in[10];
  const float* av    = (const float*)d_in[11];
  const float* avb   = (const float*)d_in[12];
  const float* fc1W  = (const float*)d_in[13];
  const float* fc1b  = (const float*)d_in[14];
  const float* fc2W  = (const float*)d_in[15];
  const float* fc2b  = (const float*)d_in[16];
  float* out = (float*)d_out;

  const int T = in_sizes[0] / kF;  // 131072

  // workspace layout: gi0T [48][T] f32 | topT [16][T] f32
  float* gi0T = (float*)d_ws;
  float* topT = gi0T + (size_t)kG * T;

  const int blocks = (T + 255) / 256;
  gi0_kernel<<<blocks, 256, 0, stream>>>(batch, Wih0, bih0, gi0T, T);
  seq_kernel<<<1, 64, 0, stream>>>(Whh0, bhh0, Wih, Whh, bih, bhh,
                                   aW, ab, av, avb, gi0T, topT, T);
  head_kernel<<<blocks, 256, 0, stream>>>(topT, fc1W, fc1b, fc2W, fc2b, out, T);
}